// Round 5
// baseline (176.307 us; speedup 1.0000x reference)
//
#include <hip/hip_runtime.h>
#include <hip/hip_bf16.h>

#define NB 8
#define L_TOT 4096
#define DIM 256
#define HEADS 8
#define HEAD_DIM 32
#define M_TOT 512
// softmax-scale folded with log2(e) so exp(x) == exp2(S)
#define QSCALE (0.17677669529663687f * 1.4426950408889634f)

typedef float f32x16 __attribute__((ext_vector_type(16)));
typedef short bf16x8 __attribute__((ext_vector_type(8)));

union BF8 { bf16x8 v; unsigned u[4]; uint2 u2[2]; uint4 u4; };

// RNE packed f32x2 -> bf16x2 (lowers to v_cvt_pk_bf16_f32)
__device__ __forceinline__ unsigned cvt2(float lo, float hi) {
    __hip_bfloat162 h = __float22bfloat162_rn(make_float2(lo, hi));
    union { __hip_bfloat162 h2; unsigned u; } un;
    un.h2 = h;
    return un.u;
}

// Frag-ready k_sum layout ("ksF"), 16384 shorts per bh:
//   element (m, c) at: (m>>5)*1024 + (c>=16)*512 + ((m&31) + 32*((c>>3)&1))*8 + (c&7)
// so the MFMA A-frag for chunk ch is a linear ds_read_b128 at lane*16.
__global__ __launch_bounds__(256) void ksum_kernel(const float* __restrict__ k,
                                                   unsigned short* __restrict__ ks) {
    const int blk = blockIdx.x;          // 1024 = bh(64) x part(16)
    const int bh = blk >> 4, part = blk & 15;
    const int b = bh >> 3, head = bh & 7;
    const float* kb = k + (size_t)b * L_TOT * DIM + head * HEAD_DIM;
    const int c0 = (threadIdx.x & 7) * 4;          // 4-float col group
    const int m = part * 32 + (threadIdx.x >> 3);  // [0,512)
    float4 s = make_float4(0.f, 0.f, 0.f, 0.f);
#pragma unroll
    for (int hq = 0; hq < 8; ++hq) {
        const float4 f = *(const float4*)(kb + (size_t)(hq * 512 + m) * DIM + c0);
        s.x += f.x; s.y += f.y; s.z += f.z; s.w += f.w;
    }
    uint2 o;
    o.x = cvt2(s.x, s.y);
    o.y = cvt2(s.z, s.w);
    const int lane = (m & 31) + 32 * ((c0 >> 3) & 1);
    const size_t off = (size_t)bh * 16384 + (size_t)(m >> 5) * 1024 +
                       (c0 >= 16 ? 512 : 0) + lane * 8 + (c0 & 7);
    *(uint2*)(ks + off) = o;
}

// One block per (bh, h). 8 waves; each wave runs its TWO 32-q-row groups as
// concurrent register streams (a: n0=0, b: n0=32) sharing the ks/V fragments
// -> 2x independent latency chains per wave at fixed occupancy.
template <bool USE_WS>
__global__ __launch_bounds__(512, 4) void attn_kernel(const float* __restrict__ q,
                                                      const float* __restrict__ kg,
                                                      const float* __restrict__ v,
                                                      const unsigned short* __restrict__ ks,
                                                      float* __restrict__ out) {
    // shorts: vF[16384] | ksF[16384] | inv[8 waves][64] floats
    constexpr int KSF_OFF = 16384;
    constexpr int INV_OFF = 32768;
    __shared__ unsigned short smem[32768 + 8 * 64 * 2];
    unsigned short* vF = smem;
    unsigned short* ksF = smem + KSF_OFF;

    const int tid = threadIdx.x;
    const int wave = tid >> 6;
    const int lane = tid & 63;
    const int ql = lane & 31;
    const int hi = lane >> 5;

    // XCD-aware swizzle (512 % 8 == 0 -> bijective)
    const int bid = blockIdx.x;
    const int wk = (bid & 7) * 64 + (bid >> 3);
    const int bh = wk >> 3, h = wk & 7;
    const int b = bh >> 3, head = bh & 7;

    // ---- stage ksF (32KB linear copy; reg-staged, b128 LDS writes) ----
    if (USE_WS) {
        const uint4* ksrc4 = (const uint4*)(ks + (size_t)bh * 16384);
        uint4* kdst4 = (uint4*)ksF;
        const uint4 t0 = ksrc4[tid], t1 = ksrc4[512 + tid];
        const uint4 t2 = ksrc4[1024 + tid], t3 = ksrc4[1536 + tid];
        kdst4[tid] = t0; kdst4[512 + tid] = t1;
        kdst4[1024 + tid] = t2; kdst4[1536 + tid] = t3;
    } else {
        const float* kb = kg + (size_t)b * L_TOT * DIM + head * HEAD_DIM;
#pragma unroll
        for (int it = 0; it < 8; ++it) {
            const int idx = it * 512 + tid;            // [0,4096)
            const int m = idx >> 3, c0 = (idx & 7) * 4;
            float4 s = make_float4(0.f, 0.f, 0.f, 0.f);
#pragma unroll
            for (int hq = 0; hq < 8; ++hq) {
                const float4 f = *(const float4*)(kb + (size_t)(hq * 512 + m) * DIM + c0);
                s.x += f.x; s.y += f.y; s.z += f.z; s.w += f.w;
            }
            uint2 o; o.x = cvt2(s.x, s.y); o.y = cvt2(s.z, s.w);
            const int ln = (m & 31) + 32 * ((c0 >> 3) & 1);
            *(uint2*)(ksF + (m >> 5) * 1024 + (c0 >= 16 ? 512 : 0) + ln * 8 + (c0 & 7)) = o;
        }
    }

    // ---- stage vF frag-linear: (m,c) -> (m>>5)*1024 + ((m>>4)&1)*512
    //                              + (c + 32*((m>>3)&1))*8 + (m&7) ----
    const float* vbase = v + ((size_t)b * L_TOT + h * M_TOT) * DIM + head * HEAD_DIM;
#pragma unroll
    for (int it = 0; it < 8; ++it) {
        const int idx = it * 512 + tid;      // [0, 4096)
        const int m = idx >> 3, c0 = (idx & 7) * 4;
        const float4 f = *(const float4*)(vbase + (size_t)m * DIM + c0);
        const unsigned w0 = cvt2(f.x, f.y), w1 = cvt2(f.z, f.w);
        unsigned short* bp = vF + (m >> 5) * 1024 + ((m >> 4) & 1) * 512 +
                             (c0 + 32 * ((m >> 3) & 1)) * 8 + (m & 7);
        bp[0]  = (unsigned short)w0;
        bp[8]  = (unsigned short)(w0 >> 16);
        bp[16] = (unsigned short)w1;
        bp[24] = (unsigned short)(w1 >> 16);
    }
    __syncthreads();

    const unsigned short* ksW = ksF + lane * 8;
    const unsigned short* vfW = vF + lane * 8;
    float* invW = (float*)(smem + INV_OFF) + wave * 64;
    const float* qbase = q + (size_t)b * L_TOT * DIM + head * HEAD_DIM;

    // ---- q B-frags for both streams (a: n0=0, b: n0=32) ----
    const int wcol = wave;
    const int na = ql, nb = 32 + ql;
    const int Lqa = (h * 8 + (na >> 3)) * 64 + wcol * 8 + (na & 7);
    const int Lqb = (h * 8 + (nb >> 3)) * 64 + wcol * 8 + (nb & 7);

    BF8 qfa0, qfa1, qfb0, qfb1;
    {
        const float* qp = qbase + (size_t)Lqa * DIM;
        const float4 f0 = *(const float4*)(qp + 8 * hi);
        const float4 f1 = *(const float4*)(qp + 8 * hi + 4);
        qfa0.u[0] = cvt2(f0.x * QSCALE, f0.y * QSCALE);
        qfa0.u[1] = cvt2(f0.z * QSCALE, f0.w * QSCALE);
        qfa0.u[2] = cvt2(f1.x * QSCALE, f1.y * QSCALE);
        qfa0.u[3] = cvt2(f1.z * QSCALE, f1.w * QSCALE);
        const float4 f2 = *(const float4*)(qp + 16 + 8 * hi);
        const float4 f3 = *(const float4*)(qp + 16 + 8 * hi + 4);
        qfa1.u[0] = cvt2(f2.x * QSCALE, f2.y * QSCALE);
        qfa1.u[1] = cvt2(f2.z * QSCALE, f2.w * QSCALE);
        qfa1.u[2] = cvt2(f3.x * QSCALE, f3.y * QSCALE);
        qfa1.u[3] = cvt2(f3.z * QSCALE, f3.w * QSCALE);
    }
    {
        const float* qp = qbase + (size_t)Lqb * DIM;
        const float4 f0 = *(const float4*)(qp + 8 * hi);
        const float4 f1 = *(const float4*)(qp + 8 * hi + 4);
        qfb0.u[0] = cvt2(f0.x * QSCALE, f0.y * QSCALE);
        qfb0.u[1] = cvt2(f0.z * QSCALE, f0.w * QSCALE);
        qfb0.u[2] = cvt2(f1.x * QSCALE, f1.y * QSCALE);
        qfb0.u[3] = cvt2(f1.z * QSCALE, f1.w * QSCALE);
        const float4 f2 = *(const float4*)(qp + 16 + 8 * hi);
        const float4 f3 = *(const float4*)(qp + 16 + 8 * hi + 4);
        qfb1.u[0] = cvt2(f2.x * QSCALE, f2.y * QSCALE);
        qfb1.u[1] = cvt2(f2.z * QSCALE, f2.w * QSCALE);
        qfb1.u[2] = cvt2(f3.x * QSCALE, f3.y * QSCALE);
        qfb1.u[3] = cvt2(f3.z * QSCALE, f3.w * QSCALE);
    }

    f32x16 Oa, Ob;
#pragma unroll
    for (int r = 0; r < 16; ++r) { Oa[r] = 0.f; Ob[r] = 0.f; }
    float lsa = 0.f, lsb = 0.f;

    // softmax (exp2, no max-subtract) + PV for one stream
    auto smPV = [&](const f32x16& S, const BF8& VB0, const BF8& VB1,
                    float& lsum, f32x16& O) {
        float p[16];
#pragma unroll
        for (int r = 0; r < 16; ++r) p[r] = __builtin_amdgcn_exp2f(S[r]);
        const float s0 = (p[0] + p[1]) + (p[2] + p[3]);
        const float s1 = (p[4] + p[5]) + (p[6] + p[7]);
        const float s2 = (p[8] + p[9]) + (p[10] + p[11]);
        const float s3 = (p[12] + p[13]) + (p[14] + p[15]);
        lsum += (s0 + s1) + (s2 + s3);

        unsigned w0 = cvt2(p[0], p[1]),   w1 = cvt2(p[2], p[3]);
        unsigned w2 = cvt2(p[4], p[5]),   w3 = cvt2(p[6], p[7]);
        unsigned w4 = cvt2(p[8], p[9]),   w5 = cvt2(p[10], p[11]);
        unsigned w6 = cvt2(p[12], p[13]), w7 = cvt2(p[14], p[15]);
        // vdst.row1 <-> vsrc.row0: builds P A-frag words (k = m ascending)
        asm("v_permlane32_swap_b32 %0, %1" : "+v"(w0), "+v"(w2));
        asm("v_permlane32_swap_b32 %0, %1" : "+v"(w1), "+v"(w3));
        asm("v_permlane32_swap_b32 %0, %1" : "+v"(w4), "+v"(w6));
        asm("v_permlane32_swap_b32 %0, %1" : "+v"(w5), "+v"(w7));
        BF8 PA0, PA1;
        PA0.u[0] = w0; PA0.u[1] = w1; PA0.u[2] = w2; PA0.u[3] = w3;
        PA1.u[0] = w4; PA1.u[1] = w5; PA1.u[2] = w6; PA1.u[3] = w7;
        O = __builtin_amdgcn_mfma_f32_32x32x16_bf16(PA0.v, VB0.v, O, 0, 0, 0);
        O = __builtin_amdgcn_mfma_f32_32x32x16_bf16(PA1.v, VB1.v, O, 0, 0, 0);
    };

#pragma unroll 2
    for (int ch = 0; ch < 16; ++ch) {
        BF8 A0, A1, VB0, VB1;  // shared by both streams
        A0.u4 = *(const uint4*)(ksW + ch * 1024);
        A1.u4 = *(const uint4*)(ksW + ch * 1024 + 512);
        VB0.u4 = *(const uint4*)(vfW + ch * 1024);
        VB1.u4 = *(const uint4*)(vfW + ch * 1024 + 512);

        f32x16 Sa;
#pragma unroll
        for (int r = 0; r < 16; ++r) Sa[r] = 0.f;
        Sa = __builtin_amdgcn_mfma_f32_32x32x16_bf16(A0.v, qfa0.v, Sa, 0, 0, 0);
        Sa = __builtin_amdgcn_mfma_f32_32x32x16_bf16(A1.v, qfa1.v, Sa, 0, 0, 0);
        smPV(Sa, VB0, VB1, lsa, Oa);

        f32x16 Sb;
#pragma unroll
        for (int r = 0; r < 16; ++r) Sb[r] = 0.f;
        Sb = __builtin_amdgcn_mfma_f32_32x32x16_bf16(A0.v, qfb0.v, Sb, 0, 0, 0);
        Sb = __builtin_amdgcn_mfma_f32_32x32x16_bf16(A1.v, qfb1.v, Sb, 0, 0, 0);
        smPV(Sb, VB0, VB1, lsb, Ob);
    }

    // row-sums across the two k-halves; redistribute 1/l via per-wave LDS
    lsa += __shfl_xor(lsa, 32, 64);
    lsb += __shfl_xor(lsb, 32, 64);
    const float inva = __builtin_amdgcn_rcpf(lsa);
    const float invb = __builtin_amdgcn_rcpf(lsb);
    if (hi == 0) { invW[ql] = inva; invW[32 + ql] = invb; }

    // O: col = c_out = ql, row(r) = (r&3) + 8*(r>>2) + 4*hi -> coalesced stores
    const int rowBase = h * 512 + wcol * 8 + 4 * hi;
    float* oa = out + ((size_t)b * L_TOT + rowBase) * DIM + head * HEAD_DIM + ql;
    float* ob = oa + (size_t)256 * DIM;  // stream b: n0=32 -> +256 rows
#pragma unroll
    for (int t = 0; t < 4; ++t) {
        const float4 iva = *(const float4*)(invW + 8 * t + 4 * hi);
        const float4 ivb = *(const float4*)(invW + 32 + 8 * t + 4 * hi);
        oa[(size_t)(t * 64 + 0) * DIM] = Oa[4 * t + 0] * iva.x;
        oa[(size_t)(t * 64 + 1) * DIM] = Oa[4 * t + 1] * iva.y;
        oa[(size_t)(t * 64 + 2) * DIM] = Oa[4 * t + 2] * iva.z;
        oa[(size_t)(t * 64 + 3) * DIM] = Oa[4 * t + 3] * iva.w;
        ob[(size_t)(t * 64 + 0) * DIM] = Ob[4 * t + 0] * ivb.x;
        ob[(size_t)(t * 64 + 1) * DIM] = Ob[4 * t + 1] * ivb.y;
        ob[(size_t)(t * 64 + 2) * DIM] = Ob[4 * t + 2] * ivb.z;
        ob[(size_t)(t * 64 + 3) * DIM] = Ob[4 * t + 3] * ivb.w;
    }
}

extern "C" void kernel_launch(void* const* d_in, const int* in_sizes, int n_in,
                              void* d_out, int out_size, void* d_ws, size_t ws_size,
                              hipStream_t stream) {
    const float* qkv = (const float*)d_in[0];
    const float* q = qkv;
    const float* k = qkv + (size_t)NB * L_TOT * DIM;
    const float* v = qkv + (size_t)2 * NB * L_TOT * DIM;
    float* out = (float*)d_out;
    const size_t ks_bytes = (size_t)NB * HEADS * M_TOT * HEAD_DIM * 2;  // 2 MB
    if (ws_size >= ks_bytes) {
        unsigned short* ks = (unsigned short*)d_ws;
        ksum_kernel<<<dim3(1024), dim3(256), 0, stream>>>(k, ks);
        attn_kernel<true><<<dim3(512), dim3(512), 0, stream>>>(q, k, v, ks, out);
    } else {
        attn_kernel<false><<<dim3(512), dim3(512), 0, stream>>>(q, k, v, nullptr, out);
    }
}